// Round 6
// baseline (1240.844 us; speedup 1.0000x reference)
//
#include <hip/hip_runtime.h>
#include <hip/hip_cooperative_groups.h>

namespace cg = cooperative_groups;

#define NU 100000
#define NI 50000
#define NE 1000000
#define D  64
#define NBI 196            // item buckets of 256
#define NBU 391            // user buckets of 256
#define NB_TOT (NBI + NBU)
#define PCHUNK 2048        // edges per partition chunk (8 per thread)
#define NCH ((NE + PCHUNK - 1) / PCHUNK)

__device__ __forceinline__ unsigned short f2bf(float f) {
    unsigned int u = __float_as_uint(f);
    u += 0x7FFFu + ((u >> 16) & 1u);   // RNE
    return (unsigned short)(u >> 16);
}
__device__ __forceinline__ float bf2f(unsigned short h) {
    return __uint_as_float(((unsigned int)h) << 16);
}

// one wave aggregates one destination node: sub=lane>>4 picks 1 of 4 edges,
// li=lane&15 picks 4 dims (ushort4). out = mean(feat[nbrs]) + self*sw.
__device__ __forceinline__ void agg_wave(const unsigned short* __restrict__ feat,
                                         const float* self, const float* __restrict__ sw,
                                         const int* __restrict__ rp, const int* __restrict__ cols,
                                         float* out, unsigned short* out_bf,
                                         int w, int sub, int li) {
    int beg = rp[w], end = rp[w + 1];
    float4 a0 = make_float4(0.f, 0.f, 0.f, 0.f);
    float4 a1 = make_float4(0.f, 0.f, 0.f, 0.f);
    for (int j0 = beg; j0 < end; j0 += 8) {
        int e0 = j0 + sub, e1 = e0 + 4;
        bool v0 = e0 < end, v1 = e1 < end;
        int c0 = 0, c1 = 0;
        if (v0) c0 = cols[e0];
        if (v1) c1 = cols[e1];
        ushort4 h0, h1;
        if (v0) h0 = *(const ushort4*)(feat + (size_t)c0 * D + li * 4);
        if (v1) h1 = *(const ushort4*)(feat + (size_t)c1 * D + li * 4);
        if (v0) { a0.x += bf2f(h0.x); a0.y += bf2f(h0.y); a0.z += bf2f(h0.z); a0.w += bf2f(h0.w); }
        if (v1) { a1.x += bf2f(h1.x); a1.y += bf2f(h1.y); a1.z += bf2f(h1.z); a1.w += bf2f(h1.w); }
    }
    a0.x += a1.x; a0.y += a1.y; a0.z += a1.z; a0.w += a1.w;
    a0.x += __shfl_xor(a0.x, 16); a0.y += __shfl_xor(a0.y, 16);
    a0.z += __shfl_xor(a0.z, 16); a0.w += __shfl_xor(a0.w, 16);
    a0.x += __shfl_xor(a0.x, 32); a0.y += __shfl_xor(a0.y, 32);
    a0.z += __shfl_xor(a0.z, 32); a0.w += __shfl_xor(a0.w, 32);
    if (sub == 0) {
        int dgr = end - beg;
        float inv = (dgr > 0) ? (1.0f / (float)dgr) : 0.0f;
        float swv = sw[w];
        float4 s = *(const float4*)(self + (size_t)w * D + li * 4);
        float4 r;
        r.x = a0.x * inv + s.x * swv;
        r.y = a0.y * inv + s.y * swv;
        r.z = a0.z * inv + s.z * swv;
        r.w = a0.w * inv + s.w * swv;
        *(float4*)(out + (size_t)w * D + li * 4) = r;
        if (out_bf) {
            ushort4 hb;
            hb.x = f2bf(r.x); hb.y = f2bf(r.y); hb.z = f2bf(r.z); hb.w = f2bf(r.w);
            *(ushort4*)(out_bf + (size_t)w * D + li * 4) = hb;
        }
    }
}

__global__ __launch_bounds__(256, 4) void mega(
        const int* __restrict__ esrc, const int* __restrict__ edst,
        const float* __restrict__ user_emb, const float* __restrict__ item_emb,
        const float* __restrict__ u_sw, const float* __restrict__ i_sw,
        float* out_u, float* out_i,
        int* bcnt, int* bbase_i, int* bbase_u, int* gcur_i, int* gcur_u,
        int* rp_i, int* rp_u, int* col_i, int* col_u,
        unsigned int* rec_i, unsigned int* rec_u,
        unsigned short* u_bf, unsigned short* i_bf,
        unsigned short* i1_bf, unsigned short* u1_bf) {
    cg::grid_group grid = cg::this_grid();
    __shared__ int smem[1280];
    const int tid = threadIdx.x;
    const int bid = blockIdx.x;
    const int nb  = gridDim.x;
    const int gtid = bid * 256 + tid;
    const int gstride = nb * 256;

    // ---- phase 0: zero bucket counters + build bf16 shadow tables ----
    for (int i = gtid; i < NB_TOT; i += gstride) bcnt[i] = 0;
    for (int i = gtid; i < NU * D / 4; i += gstride) {
        float4 f = ((const float4*)user_emb)[i];
        ushort4 h; h.x = f2bf(f.x); h.y = f2bf(f.y); h.z = f2bf(f.z); h.w = f2bf(f.w);
        ((ushort4*)u_bf)[i] = h;
    }
    for (int i = gtid; i < NI * D / 4; i += gstride) {
        float4 f = ((const float4*)item_emb)[i];
        ushort4 h; h.x = f2bf(f.x); h.y = f2bf(f.y); h.z = f2bf(f.z); h.w = f2bf(f.w);
        ((ushort4*)i_bf)[i] = h;
    }
    grid.sync();

    // ---- phase 1: bucket histograms (LDS-staged) ----
    for (int b = tid; b < NB_TOT; b += 256) smem[b] = 0;
    __syncthreads();
    for (int e = gtid; e < NE; e += gstride) {
        atomicAdd(&smem[edst[e] >> 8], 1);
        atomicAdd(&smem[NBI + (esrc[e] >> 8)], 1);
    }
    __syncthreads();
    for (int b = tid; b < NB_TOT; b += 256) {
        int v = smem[b];
        if (v) atomicAdd(&bcnt[b], v);
    }
    grid.sync();

    // ---- phase 2: exclusive scan of bucket counts (block 0) ----
    // item buckets [0,NBI) then user buckets; prefix at NBI == NE exactly,
    // so user-side bases = full prefix - NE.
    if (bid == 0) {
        int v[3]; int tot = 0;
#pragma unroll
        for (int k = 0; k < 3; k++) {
            int idx = tid * 3 + k;
            v[k] = (idx < NB_TOT) ? bcnt[idx] : 0;
            tot += v[k];
        }
        smem[tid] = tot;
        __syncthreads();
        for (int off = 1; off < 256; off <<= 1) {
            int t = (tid >= off) ? smem[tid - off] : 0;
            __syncthreads();
            smem[tid] += t;
            __syncthreads();
        }
        int run = smem[tid] - tot;   // exclusive offset
#pragma unroll
        for (int k = 0; k < 3; k++) {
            int idx = tid * 3 + k;
            if (idx < NB_TOT) {
                if (idx < NBI) { bbase_i[idx] = run; gcur_i[idx] = run; }
                else { bbase_u[idx - NBI] = run - NE; gcur_u[idx - NBI] = run - NE; }
            }
            run += v[k];
        }
        if (tid == 0) { bbase_i[NBI] = NE; bbase_u[NBU] = NE; }
    }
    grid.sync();

    // ---- phase 3: partition both sides' packed records in one pass ----
    {
        int* cnt_i = smem;                 // NBI
        int* gb_i  = smem + NBI;           // NBI
        int* cnt_u = smem + 2 * NBI;       // NBU
        int* gb_u  = smem + 2 * NBI + NBU; // NBU  (total 1174 <= 1280)
        for (int c = bid; c < NCH; c += nb) {
            for (int b = tid; b < NBI; b += 256) cnt_i[b] = 0;
            for (int b = tid; b < NBU; b += 256) cnt_u[b] = 0;
            __syncthreads();
            int dd[8], uu[8], ki[8], ku[8];
            int base = c * PCHUNK;
#pragma unroll
            for (int k = 0; k < 8; k++) {
                int j = base + tid + k * 256;
                dd[k] = -1;
                if (j < NE) {
                    dd[k] = edst[j]; uu[k] = esrc[j];
                    ki[k] = atomicAdd(&cnt_i[dd[k] >> 8], 1);
                    ku[k] = atomicAdd(&cnt_u[uu[k] >> 8], 1);
                }
            }
            __syncthreads();
            for (int b = tid; b < NBI; b += 256) { int v = cnt_i[b]; if (v) gb_i[b] = atomicAdd(&gcur_i[b], v); }
            for (int b = tid; b < NBU; b += 256) { int v = cnt_u[b]; if (v) gb_u[b] = atomicAdd(&gcur_u[b], v); }
            __syncthreads();
#pragma unroll
            for (int k = 0; k < 8; k++) {
                if (dd[k] >= 0) {
                    rec_i[gb_i[dd[k] >> 8] + ki[k]] = ((unsigned int)(dd[k] & 255) << 17) | (unsigned int)uu[k];
                    rec_u[gb_u[uu[k] >> 8] + ku[k]] = ((unsigned int)(uu[k] & 255) << 17) | (unsigned int)dd[k];
                }
            }
            __syncthreads();
        }
    }
    grid.sync();

    // ---- phase 4: per-bucket local fill -> rp + col (both sides, task loop) ----
    for (int t = bid; t < NB_TOT; t += nb) {
        bool item = t < NBI;
        int b = item ? t : t - NBI;
        const unsigned int* rec = item ? rec_i : rec_u;
        const int* bb = item ? bbase_i : bbase_u;
        int* rp  = item ? rp_i : rp_u;
        int* col = item ? col_i : col_u;
        int nn   = item ? NI : NU;
        int beg = bb[b], end = bb[b + 1];
        int* cnt = smem;
        int* off = smem + 256;
        cnt[tid] = 0;
        __syncthreads();
        for (int j = beg + tid; j < end; j += 256)
            atomicAdd(&cnt[rec[j] >> 17], 1);
        __syncthreads();
        int v = cnt[tid];
        off[tid] = v;
        __syncthreads();
        for (int o = 1; o < 256; o <<= 1) {
            int tv = (tid >= o) ? off[tid - o] : 0;
            __syncthreads();
            off[tid] += tv;
            __syncthreads();
        }
        int ex = off[tid] - v;
        int node = b * 256 + tid;
        if (node <= nn) rp[node] = beg + ex;
        cnt[tid] = ex;
        __syncthreads();
        for (int j = beg + tid; j < end; j += 256) {
            unsigned int r = rec[j];
            int p = atomicAdd(&cnt[r >> 17], 1);
            col[beg + p] = (int)(r & 0x1FFFF);
        }
        __syncthreads();
    }
    grid.sync();

    // ---- aggregation phases: wave-per-node, grid-stride ----
    const int gwave = gtid >> 6;
    const int nwave = gstride >> 6;
    const int sub = (tid >> 4) & 3;
    const int li  = tid & 15;

    // phase 5: i1 = mean(u0_bf) + i0*i_sw -> out_i + i1_bf (aliases rec; rec dead)
    for (int w = gwave; w < NI; w += nwave)
        agg_wave(u_bf, item_emb, i_sw, rp_i, col_i, out_i, i1_bf, w, sub, li);
    grid.sync();

    // phase 6: u1 = mean(i0_bf) + u0*u_sw -> out_u + u1_bf (aliases u_bf; u0_bf dead)
    for (int w = gwave; w < NU; w += nwave)
        agg_wave(i_bf, user_emb, u_sw, rp_u, col_u, out_u, u1_bf, w, sub, li);
    grid.sync();

    // phase 7: round 2, both sides fused, in-place finalize
    for (int w = gwave; w < NI + NU; w += nwave) {
        if (w < NI) agg_wave(u1_bf, out_i, i_sw, rp_i, col_i, out_i, nullptr, w, sub, li);
        else        agg_wave(i1_bf, out_u, u_sw, rp_u, col_u, out_u, nullptr, w - NI, sub, li);
    }
}

extern "C" void kernel_launch(void* const* d_in, const int* in_sizes, int n_in,
                              void* d_out, int out_size, void* d_ws, size_t ws_size,
                              hipStream_t stream) {
    const int*   esrc     = (const int*)d_in[4];
    const int*   edst     = (const int*)d_in[5];
    const float* user_emb = (const float*)d_in[0];
    const float* item_emb = (const float*)d_in[1];
    const float* u_sw     = (const float*)d_in[2];
    const float* i_sw     = (const float*)d_in[3];

    float* out_u = (float*)d_out;
    float* out_i = out_u + NU * D;

    // ---- workspace layout (~35.8 MB) ----
    int* bcnt    = (int*)d_ws;                            // NB_TOT
    int* bbase_i = bcnt + NB_TOT;                         // NBI+1
    int* bbase_u = bbase_i + NBI + 1;                     // NBU+1
    int* gcur_i  = bbase_u + NBU + 1;                     // NBI
    int* gcur_u  = gcur_i + NBI;                          // NBU
    int* rp_i    = gcur_u + NBU;                          // NI+1
    int* rp_u    = rp_i + NI + 1;                         // NU+1
    int* col_i   = rp_u + NU + 1;                         // NE
    int* col_u   = col_i + NE;                            // NE
    uintptr_t pa = ((uintptr_t)(col_u + NE) + 15) & ~(uintptr_t)15;
    unsigned int* rec_i = (unsigned int*)pa;              // NE (dead after phase 4)
    unsigned int* rec_u = rec_i + NE;                     // NE (dead after phase 4)
    unsigned short* i1_bf = (unsigned short*)rec_i;       // NI*64 us, aliases rec (6.4<=8MB)
    unsigned short* u_bf  = (unsigned short*)(rec_u + NE);// NU*64 us, 16B aligned
    unsigned short* u1_bf = u_bf;                         // aliases u_bf (u0 dead after phase 5)
    unsigned short* i_bf  = u_bf + (size_t)NU * D;        // NI*64 us

    int maxb = 0;
    hipError_t oe = hipOccupancyMaxActiveBlocksPerMultiprocessor(&maxb, mega, 256, 0);
    if (oe != hipSuccess || maxb < 1) maxb = 2;   // conservative fallback (launch_bounds guarantees 4)
    if (maxb > 8) maxb = 8;
    int grid = maxb * 256;                         // co-resident by construction

    void* args[] = {
        (void*)&esrc, (void*)&edst, (void*)&user_emb, (void*)&item_emb,
        (void*)&u_sw, (void*)&i_sw, (void*)&out_u, (void*)&out_i,
        (void*)&bcnt, (void*)&bbase_i, (void*)&bbase_u, (void*)&gcur_i, (void*)&gcur_u,
        (void*)&rp_i, (void*)&rp_u, (void*)&col_i, (void*)&col_u,
        (void*)&rec_i, (void*)&rec_u, (void*)&u_bf, (void*)&i_bf,
        (void*)&i1_bf, (void*)&u1_bf
    };
    hipLaunchCooperativeKernel(reinterpret_cast<void*>(mega), dim3(grid), dim3(256),
                               args, 0, stream);
}

// Round 7
// 337.392 us; speedup vs baseline: 3.6778x; 3.6778x over previous
//
#include <hip/hip_runtime.h>

#define NU 100000
#define NI 50000
#define NE 1000000
#define D  64
#define NBI 196            // item buckets of 256
#define NBU 391            // user buckets of 256
#define NB_TOT (NBI + NBU)
#define CHUNK 4096         // edges per k_part_both block (16 per thread)

__device__ __forceinline__ unsigned short f2bf(float f) {
    unsigned int u = __float_as_uint(f);
    u += 0x7FFFu + ((u >> 16) & 1u);   // RNE
    return (unsigned short)(u >> 16);
}
__device__ __forceinline__ float bf2f(unsigned short h) {
    return __uint_as_float(((unsigned int)h) << 16);
}

// ---- bf16 shadow of both tables in one dispatch ----
__global__ void k_tobf16_both(const float* __restrict__ uin, const float* __restrict__ iin,
                              unsigned short* __restrict__ ubf /* ibf = ubf + NU*D */) {
    int i = blockIdx.x * blockDim.x + threadIdx.x;
    const int NU4 = NU * D / 4;
    const int NT4 = (NU + NI) * D / 4;
    if (i < NT4) {
        float4 f = (i < NU4) ? ((const float4*)uin)[i] : ((const float4*)iin)[i - NU4];
        ushort4 h;
        h.x = f2bf(f.x); h.y = f2bf(f.y); h.z = f2bf(f.z); h.w = f2bf(f.w);
        ((ushort4*)ubf)[i] = h;
    }
}

// ---- bucket histograms for both partitions in one pass ----
__global__ void k_bhist(const int* __restrict__ esrc, const int* __restrict__ edst,
                        int* __restrict__ bcnt, int ne) {
    __shared__ int h[NB_TOT];
    for (int b = threadIdx.x; b < NB_TOT; b += blockDim.x) h[b] = 0;
    __syncthreads();
    int stride = gridDim.x * blockDim.x;
    for (int e = blockIdx.x * blockDim.x + threadIdx.x; e < ne; e += stride) {
        atomicAdd(&h[edst[e] >> 8], 1);
        atomicAdd(&h[NBI + (esrc[e] >> 8)], 1);
    }
    __syncthreads();
    for (int b = threadIdx.x; b < NB_TOT; b += blockDim.x) {
        int v = h[b];
        if (v) atomicAdd(&bcnt[b], v);
    }
}

// ---- both exclusive scans in one dispatch: block 0 = items, block 1 = users ----
__global__ void k_bscan_both(const int* __restrict__ bcnt,
                             int* __restrict__ bbase_i, int* __restrict__ gcur_i,
                             int* __restrict__ bbase_u, int* __restrict__ gcur_u) {
    __shared__ int s[512];
    int tid = threadIdx.x;
    const int* in = (blockIdx.x == 0) ? bcnt : bcnt + NBI;
    int nb        = (blockIdx.x == 0) ? NBI : NBU;
    int* bbase    = (blockIdx.x == 0) ? bbase_i : bbase_u;
    int* gcur     = (blockIdx.x == 0) ? gcur_i : gcur_u;
    int v = (tid < nb) ? in[tid] : 0;
    s[tid] = v;
    __syncthreads();
    for (int o = 1; o < 512; o <<= 1) {
        int t = (tid >= o) ? s[tid - o] : 0;
        __syncthreads();
        s[tid] += t;
        __syncthreads();
    }
    if (tid < nb) { int ex = s[tid] - v; bbase[tid] = ex; gcur[tid] = ex; }
    if (tid == 0) bbase[nb] = NE;
}

// ---- partition BOTH sides' packed records in one pass over the edge list ----
// rec_i entry: (dst&255)<<17 | src ; rec_u entry: (src&255)<<17 | dst
__global__ void k_part_both(const int* __restrict__ esrc, const int* __restrict__ edst,
                            int* __restrict__ gcur_i, int* __restrict__ gcur_u,
                            unsigned int* __restrict__ rec_i, unsigned int* __restrict__ rec_u) {
    __shared__ int cnt_i[NBI], gb_i[NBI], cnt_u[NBU], gb_u[NBU];
    int tid = threadIdx.x;
    for (int b = tid; b < NBI; b += 256) cnt_i[b] = 0;
    for (int b = tid; b < NBU; b += 256) cnt_u[b] = 0;
    __syncthreads();
    int base = blockIdx.x * CHUNK;
    int dd[16], uu[16], ki[16], ku[16];
#pragma unroll
    for (int k = 0; k < 16; k++) {
        int j = base + tid + k * 256;
        dd[k] = -1;
        if (j < NE) {
            dd[k] = edst[j]; uu[k] = esrc[j];
            ki[k] = atomicAdd(&cnt_i[dd[k] >> 8], 1);
            ku[k] = atomicAdd(&cnt_u[uu[k] >> 8], 1);
        }
    }
    __syncthreads();
    for (int b = tid; b < NBI; b += 256) { int v = cnt_i[b]; if (v) gb_i[b] = atomicAdd(&gcur_i[b], v); }
    for (int b = tid; b < NBU; b += 256) { int v = cnt_u[b]; if (v) gb_u[b] = atomicAdd(&gcur_u[b], v); }
    __syncthreads();
#pragma unroll
    for (int k = 0; k < 16; k++) {
        if (dd[k] >= 0) {
            rec_i[gb_i[dd[k] >> 8] + ki[k]] = ((unsigned int)(dd[k] & 255) << 17) | (unsigned int)uu[k];
            rec_u[gb_u[uu[k] >> 8] + ku[k]] = ((unsigned int)(uu[k] & 255) << 17) | (unsigned int)dd[k];
        }
    }
}

// ---- per-bucket local fill, both sides: one block per bucket task ----
__global__ void k_local_both(const unsigned int* __restrict__ rec_i, const unsigned int* __restrict__ rec_u,
                             const int* __restrict__ bbase_i, const int* __restrict__ bbase_u,
                             int* __restrict__ rp_i, int* __restrict__ rp_u,
                             int* __restrict__ col_i, int* __restrict__ col_u) {
    __shared__ int cnt[256];
    __shared__ int off[256];
    int tid = threadIdx.x;
    int t = blockIdx.x;
    bool item = t < NBI;
    int b = item ? t : t - NBI;
    const unsigned int* rec = item ? rec_i : rec_u;
    const int* bb = item ? bbase_i : bbase_u;
    int* rp  = item ? rp_i : rp_u;
    int* col = item ? col_i : col_u;
    int nn   = item ? NI : NU;
    int beg = bb[b], end = bb[b + 1];
    cnt[tid] = 0;
    __syncthreads();
    for (int j = beg + tid; j < end; j += 256)
        atomicAdd(&cnt[rec[j] >> 17], 1);
    __syncthreads();
    int v = cnt[tid];
    off[tid] = v;
    __syncthreads();
    for (int o = 1; o < 256; o <<= 1) {
        int tv = (tid >= o) ? off[tid - o] : 0;
        __syncthreads();
        off[tid] += tv;
        __syncthreads();
    }
    int ex = off[tid] - v;
    int node = b * 256 + tid;
    if (node <= nn) rp[node] = beg + ex;
    cnt[tid] = ex;
    __syncthreads();
    for (int j = beg + tid; j < end; j += 256) {
        unsigned int r = rec[j];
        int p = atomicAdd(&cnt[r >> 17], 1);
        col[beg + p] = (int)(r & 0x1FFFF);
    }
}

// ---- one wave aggregates one dst node: sub=lane>>4 picks 1 of 4 edges,
// li=lane&15 picks 4 dims (ushort4). out = mean(feat[nbrs]) + self*sw. ----
__device__ __forceinline__ void agg_wave(const unsigned short* __restrict__ feat,
                                         const float* self, const float* __restrict__ sw,
                                         const int* __restrict__ rp, const int* __restrict__ cols,
                                         float* out, unsigned short* out_bf,
                                         int w, int sub, int li) {
    int beg = rp[w], end = rp[w + 1];
    float4 a0 = make_float4(0.f, 0.f, 0.f, 0.f);
    float4 a1 = make_float4(0.f, 0.f, 0.f, 0.f);
    for (int j0 = beg; j0 < end; j0 += 8) {
        int e0 = j0 + sub, e1 = e0 + 4;
        bool v0 = e0 < end, v1 = e1 < end;
        int c0 = 0, c1 = 0;
        if (v0) c0 = cols[e0];
        if (v1) c1 = cols[e1];
        ushort4 h0, h1;
        if (v0) h0 = *(const ushort4*)(feat + (size_t)c0 * D + li * 4);
        if (v1) h1 = *(const ushort4*)(feat + (size_t)c1 * D + li * 4);
        if (v0) { a0.x += bf2f(h0.x); a0.y += bf2f(h0.y); a0.z += bf2f(h0.z); a0.w += bf2f(h0.w); }
        if (v1) { a1.x += bf2f(h1.x); a1.y += bf2f(h1.y); a1.z += bf2f(h1.z); a1.w += bf2f(h1.w); }
    }
    a0.x += a1.x; a0.y += a1.y; a0.z += a1.z; a0.w += a1.w;
    a0.x += __shfl_xor(a0.x, 16); a0.y += __shfl_xor(a0.y, 16);
    a0.z += __shfl_xor(a0.z, 16); a0.w += __shfl_xor(a0.w, 16);
    a0.x += __shfl_xor(a0.x, 32); a0.y += __shfl_xor(a0.y, 32);
    a0.z += __shfl_xor(a0.z, 32); a0.w += __shfl_xor(a0.w, 32);
    if (sub == 0) {
        int dgr = end - beg;
        float inv = (dgr > 0) ? (1.0f / (float)dgr) : 0.0f;
        float swv = sw[w];
        float4 s = *(const float4*)(self + (size_t)w * D + li * 4);
        float4 r;
        r.x = a0.x * inv + s.x * swv;
        r.y = a0.y * inv + s.y * swv;
        r.z = a0.z * inv + s.z * swv;
        r.w = a0.w * inv + s.w * swv;
        *(float4*)(out + (size_t)w * D + li * 4) = r;
        if (out_bf) {
            ushort4 hb;
            hb.x = f2bf(r.x); hb.y = f2bf(r.y); hb.z = f2bf(r.z); hb.w = f2bf(r.w);
            *(ushort4*)(out_bf + (size_t)w * D + li * 4) = hb;
        }
    }
}

// single-side agg (round 1)
__global__ void k_agg_bf(const unsigned short* __restrict__ feat, const float* self,
                         const float* __restrict__ sw, const int* __restrict__ rp,
                         const int* __restrict__ cols, float* out,
                         unsigned short* out_bf, int n_dst) {
    int w = (blockIdx.x * blockDim.x + threadIdx.x) >> 6;
    if (w >= n_dst) return;
    agg_wave(feat, self, sw, rp, cols, out, out_bf, w, (threadIdx.x >> 4) & 3, threadIdx.x & 15);
}

// fused round-2 agg: items [0,NI), users [NI,NI+NU) — independent tasks
__global__ void k_agg2(const unsigned short* __restrict__ u1_bf, const unsigned short* __restrict__ i1_bf,
                       const float* __restrict__ i_sw, const float* __restrict__ u_sw,
                       const int* __restrict__ rp_i, const int* __restrict__ rp_u,
                       const int* __restrict__ col_i, const int* __restrict__ col_u,
                       float* out_i, float* out_u) {
    int w = (blockIdx.x * blockDim.x + threadIdx.x) >> 6;
    int sub = (threadIdx.x >> 4) & 3;
    int li  = threadIdx.x & 15;
    if (w < NI)
        agg_wave(u1_bf, out_i, i_sw, rp_i, col_i, out_i, nullptr, w, sub, li);
    else if (w < NI + NU)
        agg_wave(i1_bf, out_u, u_sw, rp_u, col_u, out_u, nullptr, w - NI, sub, li);
}

extern "C" void kernel_launch(void* const* d_in, const int* in_sizes, int n_in,
                              void* d_out, int out_size, void* d_ws, size_t ws_size,
                              hipStream_t stream) {
    const float* user_emb = (const float*)d_in[0];
    const float* item_emb = (const float*)d_in[1];
    const float* u_sw     = (const float*)d_in[2];
    const float* i_sw     = (const float*)d_in[3];
    const int*   esrc     = (const int*)d_in[4];   // user endpoint
    const int*   edst     = (const int*)d_in[5];   // item endpoint

    float* out_u = (float*)d_out;          // NU*64 f32
    float* out_i = out_u + NU * D;         // NI*64 f32

    // ---- workspace layout (~35.8 MB, with aliasing) ----
    int* bcnt    = (int*)d_ws;                            // NB_TOT
    int* bbase_i = bcnt + NB_TOT;                         // NBI+1
    int* bbase_u = bbase_i + NBI + 1;                     // NBU+1
    int* gcur_i  = bbase_u + NBU + 1;                     // NBI
    int* gcur_u  = gcur_i + NBI;                          // NBU
    int* rp_i    = gcur_u + NBU;                          // NI+1
    int* rp_u    = rp_i + NI + 1;                         // NU+1
    int* col_i   = rp_u + NU + 1;                         // NE
    int* col_u   = col_i + NE;                            // NE
    uintptr_t pa = ((uintptr_t)(col_u + NE) + 15) & ~(uintptr_t)15;
    unsigned int* rec_i = (unsigned int*)pa;              // NE (dead after k_local_both)
    unsigned int* rec_u = rec_i + NE;                     // NE (dead after k_local_both)
    unsigned short* i1_bf = (unsigned short*)rec_i;       // NI*64 us, aliases rec (6.4<=8MB)
    unsigned short* u_bf  = (unsigned short*)(rec_u + NE);// NU*64 us, 16B aligned
    unsigned short* u1_bf = u_bf;                         // aliases u_bf (u0 dead after i1-agg)
    unsigned short* i_bf  = u_bf + (size_t)NU * D;        // NI*64 us (contiguous after u_bf)

    hipMemsetAsync(bcnt, 0, NB_TOT * sizeof(int), stream);

    const int B = 256;

    // ---- CSR build (5 dispatches) ----
    k_bhist<<<512, B, 0, stream>>>(esrc, edst, bcnt, NE);
    k_bscan_both<<<2, 512, 0, stream>>>(bcnt, bbase_i, gcur_i, bbase_u, gcur_u);
    k_part_both<<<(NE + CHUNK - 1) / CHUNK, B, 0, stream>>>(esrc, edst, gcur_i, gcur_u, rec_i, rec_u);
    k_local_both<<<NB_TOT, B, 0, stream>>>(rec_i, rec_u, bbase_i, bbase_u, rp_i, rp_u, col_i, col_u);

    // ---- bf16 shadows (1 dispatch; u_bf and i_bf are contiguous) ----
    k_tobf16_both<<<((NU + NI) * D / 4 + B - 1) / B, B, 0, stream>>>(user_emb, item_emb, u_bf);

    int gi = (NI + 3) / 4;
    int gu = (NU + 3) / 4;

    // ---- round 1 (order matters: i1-agg reads u_bf before u1-agg overwrites it) ----
    // i1 = mean(u0_bf) + i0*i_sw -> out_i + i1_bf
    k_agg_bf<<<gi, B, 0, stream>>>(u_bf, item_emb, i_sw, rp_i, col_i, out_i, i1_bf, NI);
    // u1 = mean(i0_bf) + u0*u_sw -> out_u + u1_bf (aliases u_bf)
    k_agg_bf<<<gu, B, 0, stream>>>(i_bf, user_emb, u_sw, rp_u, col_u, out_u, u1_bf, NU);

    // ---- round 2, both sides fused, in-place finalize ----
    k_agg2<<<(NI + NU + 3) / 4, B, 0, stream>>>(u1_bf, i1_bf, i_sw, u_sw,
                                                rp_i, rp_u, col_i, col_u, out_i, out_u);
}

// Round 8
// 278.247 us; speedup vs baseline: 4.4595x; 1.2126x over previous
//
#include <hip/hip_runtime.h>

#define NU 100000
#define NI 50000
#define NE 1000000
#define D  64
#define NBI 196            // item buckets of 256
#define NBU 391            // user buckets of 256
#define NB_TOT (NBI + NBU)
#define CHUNK 4096         // edges per k_part_both block (16 per thread)

__device__ __forceinline__ unsigned short f2bf(float f) {
    unsigned int u = __float_as_uint(f);
    u += 0x7FFFu + ((u >> 16) & 1u);   // RNE
    return (unsigned short)(u >> 16);
}
__device__ __forceinline__ float bf2f(unsigned short h) {
    return __uint_as_float(((unsigned int)h) << 16);
}

// ---- bucket histograms for both partitions in one pass ----
__global__ void k_bhist(const int* __restrict__ esrc, const int* __restrict__ edst,
                        int* __restrict__ bcnt, int ne) {
    __shared__ int h[NB_TOT];
    for (int b = threadIdx.x; b < NB_TOT; b += blockDim.x) h[b] = 0;
    __syncthreads();
    int stride = gridDim.x * blockDim.x;
    for (int e = blockIdx.x * blockDim.x + threadIdx.x; e < ne; e += stride) {
        atomicAdd(&h[edst[e] >> 8], 1);
        atomicAdd(&h[NBI + (esrc[e] >> 8)], 1);
    }
    __syncthreads();
    for (int b = threadIdx.x; b < NB_TOT; b += blockDim.x) {
        int v = h[b];
        if (v) atomicAdd(&bcnt[b], v);
    }
}

// ---- both exclusive scans in one dispatch: block 0 = items, block 1 = users ----
__global__ void k_bscan_both(const int* __restrict__ bcnt,
                             int* __restrict__ bbase_i, int* __restrict__ gcur_i,
                             int* __restrict__ bbase_u, int* __restrict__ gcur_u) {
    __shared__ int s[512];
    int tid = threadIdx.x;
    const int* in = (blockIdx.x == 0) ? bcnt : bcnt + NBI;
    int nb        = (blockIdx.x == 0) ? NBI : NBU;
    int* bbase    = (blockIdx.x == 0) ? bbase_i : bbase_u;
    int* gcur     = (blockIdx.x == 0) ? gcur_i : gcur_u;
    int v = (tid < nb) ? in[tid] : 0;
    s[tid] = v;
    __syncthreads();
    for (int o = 1; o < 512; o <<= 1) {
        int t = (tid >= o) ? s[tid - o] : 0;
        __syncthreads();
        s[tid] += t;
        __syncthreads();
    }
    if (tid < nb) { int ex = s[tid] - v; bbase[tid] = ex; gcur[tid] = ex; }
    if (tid == 0) bbase[nb] = NE;
}

// ---- partition BOTH sides' packed records in one pass over the edge list ----
__global__ void k_part_both(const int* __restrict__ esrc, const int* __restrict__ edst,
                            int* __restrict__ gcur_i, int* __restrict__ gcur_u,
                            unsigned int* __restrict__ rec_i, unsigned int* __restrict__ rec_u) {
    __shared__ int cnt_i[NBI], gb_i[NBI], cnt_u[NBU], gb_u[NBU];
    int tid = threadIdx.x;
    for (int b = tid; b < NBI; b += 256) cnt_i[b] = 0;
    for (int b = tid; b < NBU; b += 256) cnt_u[b] = 0;
    __syncthreads();
    int base = blockIdx.x * CHUNK;
    int dd[16], uu[16], ki[16], ku[16];
#pragma unroll
    for (int k = 0; k < 16; k++) {
        int j = base + tid + k * 256;
        dd[k] = -1;
        if (j < NE) {
            dd[k] = edst[j]; uu[k] = esrc[j];
            ki[k] = atomicAdd(&cnt_i[dd[k] >> 8], 1);
            ku[k] = atomicAdd(&cnt_u[uu[k] >> 8], 1);
        }
    }
    __syncthreads();
    for (int b = tid; b < NBI; b += 256) { int v = cnt_i[b]; if (v) gb_i[b] = atomicAdd(&gcur_i[b], v); }
    for (int b = tid; b < NBU; b += 256) { int v = cnt_u[b]; if (v) gb_u[b] = atomicAdd(&gcur_u[b], v); }
    __syncthreads();
#pragma unroll
    for (int k = 0; k < 16; k++) {
        if (dd[k] >= 0) {
            rec_i[gb_i[dd[k] >> 8] + ki[k]] = ((unsigned int)(dd[k] & 255) << 17) | (unsigned int)uu[k];
            rec_u[gb_u[uu[k] >> 8] + ku[k]] = ((unsigned int)(uu[k] & 255) << 17) | (unsigned int)dd[k];
        }
    }
}

// ---- per-bucket local fill, both sides: one block per bucket task ----
__global__ void k_local_both(const unsigned int* __restrict__ rec_i, const unsigned int* __restrict__ rec_u,
                             const int* __restrict__ bbase_i, const int* __restrict__ bbase_u,
                             int* __restrict__ rp_i, int* __restrict__ rp_u,
                             int* __restrict__ col_i, int* __restrict__ col_u) {
    __shared__ int cnt[256];
    __shared__ int off[256];
    int tid = threadIdx.x;
    int t = blockIdx.x;
    bool item = t < NBI;
    int b = item ? t : t - NBI;
    const unsigned int* rec = item ? rec_i : rec_u;
    const int* bb = item ? bbase_i : bbase_u;
    int* rp  = item ? rp_i : rp_u;
    int* col = item ? col_i : col_u;
    int nn   = item ? NI : NU;
    int beg = bb[b], end = bb[b + 1];
    cnt[tid] = 0;
    __syncthreads();
    for (int j = beg + tid; j < end; j += 256)
        atomicAdd(&cnt[rec[j] >> 17], 1);
    __syncthreads();
    int v = cnt[tid];
    off[tid] = v;
    __syncthreads();
    for (int o = 1; o < 256; o <<= 1) {
        int tv = (tid >= o) ? off[tid - o] : 0;
        __syncthreads();
        off[tid] += tv;
        __syncthreads();
    }
    int ex = off[tid] - v;
    int node = b * 256 + tid;
    if (node <= nn) rp[node] = beg + ex;
    cnt[tid] = ex;
    __syncthreads();
    for (int j = beg + tid; j < end; j += 256) {
        unsigned int r = rec[j];
        int p = atomicAdd(&cnt[r >> 17], 1);
        col[beg + p] = (int)(r & 0x1FFFF);
    }
}

// ---- agg, 16 lanes per node (4 nodes/wave): f32 gather version ----
// li = lane&15 owns dims [li*4, li*4+4); lb = lane&48 = group base for shfl.
// cols prefetched 16-wide in one load; all gathers independent; no reduce epilogue.
__device__ __forceinline__ void agg_g_f32(const float* __restrict__ feat,
        const float* __restrict__ self, const float* __restrict__ sw,
        const int* __restrict__ rp, const int* __restrict__ cols,
        float* __restrict__ out, unsigned short* __restrict__ out_bf,
        int n, int li, int lb) {
    int beg = rp[n], end = rp[n + 1];
    float4 a = make_float4(0.f, 0.f, 0.f, 0.f);
    for (int j0 = beg; j0 < end; j0 += 16) {
        int cv = (j0 + li < end) ? cols[j0 + li] : 0;   // one load covers 16 edges
        int nj = end - j0; if (nj > 16) nj = 16;
        int j = 0;
        for (; j + 4 <= nj; j += 4) {
            int c0 = __shfl(cv, lb + j,     64);
            int c1 = __shfl(cv, lb + j + 1, 64);
            int c2 = __shfl(cv, lb + j + 2, 64);
            int c3 = __shfl(cv, lb + j + 3, 64);
            float4 f0 = *(const float4*)(feat + (size_t)c0 * D + li * 4);
            float4 f1 = *(const float4*)(feat + (size_t)c1 * D + li * 4);
            float4 f2 = *(const float4*)(feat + (size_t)c2 * D + li * 4);
            float4 f3 = *(const float4*)(feat + (size_t)c3 * D + li * 4);
            a.x += f0.x + f1.x + f2.x + f3.x;
            a.y += f0.y + f1.y + f2.y + f3.y;
            a.z += f0.z + f1.z + f2.z + f3.z;
            a.w += f0.w + f1.w + f2.w + f3.w;
        }
        for (; j < nj; ++j) {
            int c = __shfl(cv, lb + j, 64);
            float4 f = *(const float4*)(feat + (size_t)c * D + li * 4);
            a.x += f.x; a.y += f.y; a.z += f.z; a.w += f.w;
        }
    }
    int dgr = end - beg;
    float inv = (dgr > 0) ? (1.0f / (float)dgr) : 0.0f;
    float swv = sw[n];
    float4 s = *(const float4*)(self + (size_t)n * D + li * 4);
    float4 r;
    r.x = a.x * inv + s.x * swv;
    r.y = a.y * inv + s.y * swv;
    r.z = a.z * inv + s.z * swv;
    r.w = a.w * inv + s.w * swv;
    *(float4*)(out + (size_t)n * D + li * 4) = r;
    if (out_bf) {
        ushort4 hb;
        hb.x = f2bf(r.x); hb.y = f2bf(r.y); hb.z = f2bf(r.z); hb.w = f2bf(r.w);
        *(ushort4*)(out_bf + (size_t)n * D + li * 4) = hb;
    }
}

// ---- same structure, bf16 gather version (round 2) ----
__device__ __forceinline__ void agg_g_bf(const unsigned short* __restrict__ feat,
        const float* __restrict__ self, const float* __restrict__ sw,
        const int* __restrict__ rp, const int* __restrict__ cols,
        float* __restrict__ out, int n, int li, int lb) {
    int beg = rp[n], end = rp[n + 1];
    float4 a = make_float4(0.f, 0.f, 0.f, 0.f);
    for (int j0 = beg; j0 < end; j0 += 16) {
        int cv = (j0 + li < end) ? cols[j0 + li] : 0;
        int nj = end - j0; if (nj > 16) nj = 16;
        int j = 0;
        for (; j + 4 <= nj; j += 4) {
            int c0 = __shfl(cv, lb + j,     64);
            int c1 = __shfl(cv, lb + j + 1, 64);
            int c2 = __shfl(cv, lb + j + 2, 64);
            int c3 = __shfl(cv, lb + j + 3, 64);
            ushort4 h0 = *(const ushort4*)(feat + (size_t)c0 * D + li * 4);
            ushort4 h1 = *(const ushort4*)(feat + (size_t)c1 * D + li * 4);
            ushort4 h2 = *(const ushort4*)(feat + (size_t)c2 * D + li * 4);
            ushort4 h3 = *(const ushort4*)(feat + (size_t)c3 * D + li * 4);
            a.x += bf2f(h0.x) + bf2f(h1.x) + bf2f(h2.x) + bf2f(h3.x);
            a.y += bf2f(h0.y) + bf2f(h1.y) + bf2f(h2.y) + bf2f(h3.y);
            a.z += bf2f(h0.z) + bf2f(h1.z) + bf2f(h2.z) + bf2f(h3.z);
            a.w += bf2f(h0.w) + bf2f(h1.w) + bf2f(h2.w) + bf2f(h3.w);
        }
        for (; j < nj; ++j) {
            int c = __shfl(cv, lb + j, 64);
            ushort4 h = *(const ushort4*)(feat + (size_t)c * D + li * 4);
            a.x += bf2f(h.x); a.y += bf2f(h.y); a.z += bf2f(h.z); a.w += bf2f(h.w);
        }
    }
    int dgr = end - beg;
    float inv = (dgr > 0) ? (1.0f / (float)dgr) : 0.0f;
    float swv = sw[n];
    float4 s = *(const float4*)(self + (size_t)n * D + li * 4);
    float4 r;
    r.x = a.x * inv + s.x * swv;
    r.y = a.y * inv + s.y * swv;
    r.z = a.z * inv + s.z * swv;
    r.w = a.w * inv + s.w * swv;
    *(float4*)(out + (size_t)n * D + li * 4) = r;
}

// ---- round 1, both sides fused: gather f32 inputs, write f32 + bf16 shadows ----
__global__ void k_agg_r1(const float* __restrict__ user_emb, const float* __restrict__ item_emb,
                         const float* __restrict__ u_sw, const float* __restrict__ i_sw,
                         const int* __restrict__ rp_i, const int* __restrict__ rp_u,
                         const int* __restrict__ col_i, const int* __restrict__ col_u,
                         float* out_i, float* out_u,
                         unsigned short* i1_bf, unsigned short* u1_bf) {
    int g  = (blockIdx.x * blockDim.x + threadIdx.x) >> 4;
    int li = threadIdx.x & 15;
    int lb = threadIdx.x & 48;
    if (g < NI)
        agg_g_f32(user_emb, item_emb, i_sw, rp_i, col_i, out_i, i1_bf, g, li, lb);
    else if (g < NI + NU)
        agg_g_f32(item_emb, user_emb, u_sw, rp_u, col_u, out_u, u1_bf, g - NI, li, lb);
}

// ---- round 2, both sides fused: gather bf16 shadows, in-place f32 finalize ----
__global__ void k_agg_r2(const unsigned short* __restrict__ u1_bf, const unsigned short* __restrict__ i1_bf,
                         const float* __restrict__ u_sw, const float* __restrict__ i_sw,
                         const int* __restrict__ rp_i, const int* __restrict__ rp_u,
                         const int* __restrict__ col_i, const int* __restrict__ col_u,
                         float* out_i, float* out_u) {
    int g  = (blockIdx.x * blockDim.x + threadIdx.x) >> 4;
    int li = threadIdx.x & 15;
    int lb = threadIdx.x & 48;
    if (g < NI)
        agg_g_bf(u1_bf, out_i, i_sw, rp_i, col_i, out_i, g, li, lb);
    else if (g < NI + NU)
        agg_g_bf(i1_bf, out_u, u_sw, rp_u, col_u, out_u, g - NI, li, lb);
}

extern "C" void kernel_launch(void* const* d_in, const int* in_sizes, int n_in,
                              void* d_out, int out_size, void* d_ws, size_t ws_size,
                              hipStream_t stream) {
    const float* user_emb = (const float*)d_in[0];
    const float* item_emb = (const float*)d_in[1];
    const float* u_sw     = (const float*)d_in[2];
    const float* i_sw     = (const float*)d_in[3];
    const int*   esrc     = (const int*)d_in[4];   // user endpoint
    const int*   edst     = (const int*)d_in[5];   // item endpoint

    float* out_u = (float*)d_out;          // NU*64 f32
    float* out_i = out_u + NU * D;         // NI*64 f32

    // ---- workspace layout (~27.8 MB; fits the proven 35.8 MB footprint) ----
    int* bcnt    = (int*)d_ws;                            // NB_TOT
    int* bbase_i = bcnt + NB_TOT;                         // NBI+1
    int* bbase_u = bbase_i + NBI + 1;                     // NBU+1
    int* gcur_i  = bbase_u + NBU + 1;                     // NBI
    int* gcur_u  = gcur_i + NBI;                          // NBU
    int* rp_i    = gcur_u + NBU;                          // NI+1
    int* rp_u    = rp_i + NI + 1;                         // NU+1
    int* col_i   = rp_u + NU + 1;                         // NE (4 MB)
    int* col_u   = col_i + NE;                            // NE (4 MB)
    uintptr_t pa = ((uintptr_t)(col_u + NE) + 15) & ~(uintptr_t)15;
    unsigned short* u1_bf = (unsigned short*)pa;          // NU*64 us = 12.8 MB
    unsigned short* i1_bf = u1_bf + (size_t)NU * D;       // NI*64 us = 6.4 MB
    // rec_i/rec_u (4 MB each) alias the first 8 MB of u1_bf — dead before r1 writes it
    unsigned int* rec_i = (unsigned int*)pa;              // NE
    unsigned int* rec_u = rec_i + NE;                     // NE

    hipMemsetAsync(bcnt, 0, NB_TOT * sizeof(int), stream);

    const int B = 256;

    // ---- CSR build (4 dispatches) ----
    k_bhist<<<512, B, 0, stream>>>(esrc, edst, bcnt, NE);
    k_bscan_both<<<2, 512, 0, stream>>>(bcnt, bbase_i, gcur_i, bbase_u, gcur_u);
    k_part_both<<<(NE + CHUNK - 1) / CHUNK, B, 0, stream>>>(esrc, edst, gcur_i, gcur_u, rec_i, rec_u);
    k_local_both<<<NB_TOT, B, 0, stream>>>(rec_i, rec_u, bbase_i, bbase_u, rp_i, rp_u, col_i, col_u);

    // ---- aggregation: 16 lanes/node; grid = (NI+NU) groups ----
    int gblocks = ((NI + NU) * 16 + B - 1) / B;   // 9375

    // round 1: i1 = mean(u0) + i0*sw -> out_i + i1_bf ; u1 = mean(i0) + u0*sw -> out_u + u1_bf
    k_agg_r1<<<gblocks, B, 0, stream>>>(user_emb, item_emb, u_sw, i_sw,
                                        rp_i, rp_u, col_i, col_u,
                                        out_i, out_u, i1_bf, u1_bf);
    // round 2: i2 = mean(u1_bf) + i1*sw ; u2 = mean(i1_bf) + u1*sw (in place)
    k_agg_r2<<<gblocks, B, 0, stream>>>(u1_bf, i1_bf, u_sw, i_sw,
                                        rp_i, rp_u, col_i, col_u,
                                        out_i, out_u);
}